// Round 2
// baseline (148.095 us; speedup 1.0000x reference)
//
#include <hip/hip_runtime.h>

#define TPB 512

// Shapes (all fp32): x(8,14,14,32,16) a(8,14,14,32) W(288,32,16) beta_u(32) beta_a(32)
// out (fp32): p_out(8,6,6,32,16)=147456 then a_out(8,6,6,32)=9216.
// One block per output position (8*6*6=288). 512 thr = 16 n-slices x 32 c.
__global__ __launch_bounds__(TPB) void convcaps_kernel(
    const float* __restrict__ xg,
    const float* __restrict__ ag,
    const float* __restrict__ wg,
    const float* __restrict__ bu,
    const float* __restrict__ ba,
    float* __restrict__ outp)
{
    __shared__ __align__(16) float pose_s[4608];   // [288][16] fp32
    __shared__ float a_s[288];
    __shared__ __align__(16) float scratch[8448];  // 8 waves x 32 c x 33 (16 mu + 16 var + pad)
    __shared__ float rsum_part[256];               // 8 waves x 32 c
    __shared__ float mu_tab[512];                  // [c][p]
    __shared__ float i2s_tab[512];                 // 1/(2*sigma)
    __shared__ float aout_tab[32];
    __shared__ float Kc_tab[32];                   // 0.5*sum_p log(sig) - log(a_out)

    const int tid = threadIdx.x;
    const int pos = blockIdx.x;
    const int bb  = pos / 36;
    const int rem = pos % 36;
    const int yy  = rem / 6;
    const int xx  = rem % 6;

    // ---- stage pose + a_in into LDS ----
    #pragma unroll
    for (int wi = 0; wi < 9; ++wi) {
        const int kh = wi / 3, kw = wi % 3;
        const float* src =
            xg + (size_t)((((bb * 14) + (2 * yy + kh)) * 14 + (2 * xx + kw)) * 32) * 16;
        pose_s[wi * 512 + tid] = src[tid];
    }
    if (tid < 288) {
        const int wi = tid >> 5, bi = tid & 31;
        const int kh = wi / 3, kw = wi % 3;
        a_s[tid] = ag[(size_t)(((bb * 14) + (2 * yy + kh)) * 14 + (2 * xx + kw)) * 32 + bi];
    }
    __syncthreads();

    const int c    = tid & 31;   // capsule-out index
    const int s    = tid >> 5;   // n-slice 0..15 (18 n each)
    const int lane = tid & 63;
    const int wv   = tid >> 6;   // wave 0..7
    const float4* wp = (const float4*)wg;

    for (int it = 0; it < 3; ++it) {
        // hoisted per-c routing state from previous iteration
        float mu_c[16], i2s_c[16], Kc = 0.f;
        if (it > 0) {
            #pragma unroll
            for (int p = 0; p < 16; ++p) {
                mu_c[p]  = mu_tab[c * 16 + p];
                i2s_c[p] = i2s_tab[c * 16 + p];
            }
            Kc = Kc_tab[c];
        }
        float macc[16], vacc[16], rs = 0.f;
        #pragma unroll
        for (int p = 0; p < 16; ++p) { macc[p] = 0.f; vacc[p] = 0.f; }

        // ---- fused E+M pass over this thread's 18 n values ----
        for (int k = 0; k < 18; ++k) {
            const int n = s * 18 + k;
            // pose fragment (broadcast across the 32 c-lanes)
            const float4* pp = (const float4*)&pose_s[n << 4];
            float pf[16];
            float4 q;
            q = pp[0]; pf[0]=q.x; pf[1]=q.y; pf[2]=q.z;  pf[3]=q.w;
            q = pp[1]; pf[4]=q.x; pf[5]=q.y; pf[6]=q.z;  pf[7]=q.w;
            q = pp[2]; pf[8]=q.x; pf[9]=q.y; pf[10]=q.z; pf[11]=q.w;
            q = pp[3]; pf[12]=q.x; pf[13]=q.y; pf[14]=q.z; pf[15]=q.w;
            // weights W[n][c][0..15], 64B per thread, coalesced over c-lanes
            const int wbase = (n * 32 + c) * 4;
            float wf[16];
            float4 w0 = wp[wbase + 0]; wf[0]=w0.x;  wf[1]=w0.y;  wf[2]=w0.z;  wf[3]=w0.w;
            float4 w1 = wp[wbase + 1]; wf[4]=w1.x;  wf[5]=w1.y;  wf[6]=w1.z;  wf[7]=w1.w;
            float4 w2 = wp[wbase + 2]; wf[8]=w2.x;  wf[9]=w2.y;  wf[10]=w2.z; wf[11]=w2.w;
            float4 w3 = wp[wbase + 3]; wf[12]=w3.x; wf[13]=w3.y; wf[14]=w3.z; wf[15]=w3.w;
            // v = pose(4x4) @ W(4x4), flattened p = i*4+l
            float v[16];
            #pragma unroll
            for (int i = 0; i < 4; ++i)
                #pragma unroll
                for (int l = 0; l < 4; ++l)
                    v[i*4+l] = pf[i*4+0] * wf[0*4+l] + pf[i*4+1] * wf[1*4+l]
                             + pf[i*4+2] * wf[2*4+l] + pf[i*4+3] * wf[3*4+l];
            float r;
            if (it == 0) {
                r = a_s[n] * 0.03125f;  // (1/C) * a_in
            } else {
                // ln_ap = -sum_p (v-mu)^2/(2 sig) - Kc   (c-independent consts dropped)
                float t = 0.f;
                #pragma unroll
                for (int p = 0; p < 16; ++p) {
                    float d = v[p] - mu_c[p];
                    t = fmaf(d * d, i2s_c[p], t);
                }
                float lnap = -t - Kc;
                // softmax over the 32 c-lanes (half-wave group, lockstep in k)
                float m = lnap;
                #pragma unroll
                for (int msk = 16; msk >= 1; msk >>= 1) m = fmaxf(m, __shfl_xor(m, msk));
                float e = __expf(lnap - m);
                float sum = e;
                #pragma unroll
                for (int msk = 16; msk >= 1; msk >>= 1) sum += __shfl_xor(sum, msk);
                r = e / sum;
            }
            rs += r;
            #pragma unroll
            for (int p = 0; p < 16; ++p) {
                float rv = r * v[p];
                macc[p] += rv;                      // sum r*v
                vacc[p] = fmaf(rv, v[p], vacc[p]);  // sum r*v^2
            }
        }

        // ---- reduce the 16 n-slices: shfl pairs, then LDS across 8 waves ----
        #pragma unroll
        for (int p = 0; p < 16; ++p) {
            macc[p] += __shfl_xor(macc[p], 32);
            vacc[p] += __shfl_xor(vacc[p], 32);
        }
        rs += __shfl_xor(rs, 32);
        if (lane < 32) {  // c = lane
            const int base = (wv * 32 + lane) * 33;  // +33 stride: conflict-free
            #pragma unroll
            for (int p = 0; p < 16; ++p) {
                scratch[base + p]      = macc[p];
                scratch[base + 16 + p] = vacc[p];
            }
            rsum_part[wv * 32 + lane] = rs;
        }
        __syncthreads();

        // ---- finalize: thread = (fc, fp) covers all 32x16 (c,p) ----
        const int fc = tid >> 4, fp = tid & 15;
        float ms = 0.f, vs = 0.f, rsc = 0.f;
        #pragma unroll
        for (int w = 0; w < 8; ++w) {
            ms  += scratch[(w * 32 + fc) * 33 + fp];
            vs  += scratch[(w * 32 + fc) * 33 + 16 + fp];
            rsc += rsum_part[w * 32 + fc];
        }
        const float inv = 1.f / (rsc + 1e-6f);
        const float S   = rsc * inv;                       // sum_n coeff
        const float mu  = ms * inv;
        const float sig = vs * inv - mu * mu * (2.f - S) + 1e-6f;
        const float lg  = __logf(sig);
        float lgs = lg;  // sum over the 16 p-lanes sharing fc
        #pragma unroll
        for (int msk = 8; msk >= 1; msk >>= 1) lgs += __shfl_xor(lgs, msk);
        const float buv  = bu[fc];
        const float bav  = ba[fc];
        const float cost = rsc * (16.f * buv + 0.5f * lgs);
        const float ao   = 1.f / (1.f + __expf(-0.001f * (bav - cost)));

        mu_tab[fc * 16 + fp]  = mu;
        i2s_tab[fc * 16 + fp] = 0.5f / sig;
        if (fp == 0) {
            aout_tab[fc] = ao;
            Kc_tab[fc]   = 0.5f * lgs - __logf(ao);
        }

        if (it == 2) {
            outp[(size_t)pos * 512 + tid] = mu;                 // p_out: pos*512 + c*16 + p
            if (fp == 0) outp[147456 + (size_t)pos * 32 + fc] = ao;
        }
        __syncthreads();  // tabs visible before next iteration's hoisted reads
    }
}

extern "C" void kernel_launch(void* const* d_in, const int* in_sizes, int n_in,
                              void* d_out, int out_size, void* d_ws, size_t ws_size,
                              hipStream_t stream) {
    (void)in_sizes; (void)n_in; (void)out_size; (void)d_ws; (void)ws_size;
    const float* x  = (const float*)d_in[0];
    const float* a  = (const float*)d_in[1];
    const float* w  = (const float*)d_in[2];
    const float* bu = (const float*)d_in[3];
    const float* ba = (const float*)d_in[4];
    float* out = (float*)d_out;
    convcaps_kernel<<<dim3(288), dim3(TPB), 0, stream>>>(x, a, w, bu, ba, out);
}